// Round 1
// baseline (83.708 us; speedup 1.0000x reference)
//
#include <hip/hip_runtime.h>
#include <math.h>

#define N_ATOMS 21
#define DESC 210      // 21*20/2 descriptors
#define NPAIR2 105    // DESC/2 (float2 granules per row)
#define T_ROWS 12000
#define BATCH 64
// q = sqrt(5)/sig, sig=10 ; k0 = 5/(3*sig^2) = 1/60 ; STD=1, C=0

#define NCHUNK 125    // t-chunks
#define CHROWS 96     // rows per chunk = 24 iters * 4 groups
#define NPAIRBLK 32   // molecule pairs (2 molecules per block)

// ---------------- K1: descriptors xs[m][210] = 1/dist ----------------
__global__ __launch_bounds__(256) void k_desc(const float* __restrict__ Rs,
                                              float* __restrict__ xs) {
    int m = blockIdx.x;
    __shared__ float R[N_ATOMS * 3];
    int tid = threadIdx.x;
    if (tid < N_ATOMS * 3) R[tid] = Rs[m * N_ATOMS * 3 + tid];
    __syncthreads();
    if (tid < DESC) {
        int p = tid;
        int i = (int)((1.0f + sqrtf(1.0f + 8.0f * (float)p)) * 0.5f);
        while (i * (i - 1) / 2 > p) --i;
        while ((i + 1) * i / 2 <= p) ++i;
        int j = p - i * (i - 1) / 2;
        float dx = R[i * 3 + 0] - R[j * 3 + 0];
        float dy = R[i * 3 + 1] - R[j * 3 + 1];
        float dz = R[i * 3 + 2] - R[j * 3 + 2];
        float d = sqrtf(dx * dx + dy * dy + dz * dz);
        xs[m * DESC + p] = 1.0f / d;
    }
}

// ---------------- K2: main MxT loop ----------------
// 1 wave per block; 4 groups of 16 lanes; each group owns one training row
// per iteration; 2 molecules per block. Partial F1/F2/Es per (m, chunk).
__global__ __launch_bounds__(64) void k_main(const float* __restrict__ xs_train,
                                             const float* __restrict__ Jx,
                                             const float* __restrict__ xs,
                                             float* __restrict__ pf1,
                                             float* __restrict__ pf2,
                                             float* __restrict__ pes) {
    const int bid = blockIdx.x;
    const int chunk = bid >> 5;   // t-chunk (chunk-major => L2 sharing across pairs)
    const int pair = bid & 31;
    const int m0 = pair * 2, m1 = m0 + 1;
    const int lane = threadIdx.x;
    const int gl = lane & 15;     // lane within 16-lane group
    const int g = lane >> 4;      // group id 0..3

    const float q = 0.22360679774997896f;  // sqrt(5)/10
    const float k0 = 1.0f / 60.0f;         // 5/(3*sig^2)
    const float q2 = q * q;

    // per-lane molecule descriptor slots: slot k covers float2 granule k*16+gl
    float2 a0[7], a1[7];
    float2 f1a0[7], f1a1[7], f2a0[7], f2a1[7];
    const bool valid6 = (96 + gl) < NPAIR2;  // slots k<6 always valid
#pragma unroll
    for (int k = 0; k < 7; k++) {
        int pidx = k * 16 + gl;
        int d = 2 * ((pidx < NPAIR2) ? pidx : (NPAIR2 - 1));
        float2 v0 = *(const float2*)&xs[m0 * DESC + d];
        float2 v1 = *(const float2*)&xs[m1 * DESC + d];
        bool v = (pidx < NPAIR2);
        a0[k] = v ? v0 : make_float2(0.f, 0.f);
        a1[k] = v ? v1 : make_float2(0.f, 0.f);
        f1a0[k] = make_float2(0.f, 0.f); f1a1[k] = make_float2(0.f, 0.f);
        f2a0[k] = make_float2(0.f, 0.f); f2a1[k] = make_float2(0.f, 0.f);
    }
    float es0 = 0.f, es1 = 0.f;

    const int t0 = chunk * CHROWS + g;
#pragma unroll 1
    for (int it = 0; it < CHROWS / 4; ++it) {
        const int t = t0 + it * 4;
        const size_t rb = (size_t)t * DESC + 2 * gl;  // lane base (elements)
        float2 b[7], jx[7];
#pragma unroll
        for (int k = 0; k < 6; k++) {                 // always-valid slots
            b[k] = *(const float2*)&xs_train[rb + 32 * k];
            jx[k] = *(const float2*)&Jx[rb + 32 * k];
        }
        {   // slot 6: clamp + mask
            size_t rr = (size_t)t * DESC + 2 * (valid6 ? (96 + gl) : (NPAIR2 - 1));
            float2 bb = *(const float2*)&xs_train[rr];
            float2 jj = *(const float2*)&Jx[rr];
            b[6] = valid6 ? bb : make_float2(0.f, 0.f);
            jx[6] = valid6 ? jj : make_float2(0.f, 0.f);
        }

        float s0 = 0.f, dot0 = 0.f, s1 = 0.f, dot1 = 0.f;
#pragma unroll
        for (int k = 0; k < 7; k++) {
            float dx = a0[k].x - b[k].x, dy = a0[k].y - b[k].y;
            s0 = fmaf(dx, dx, s0); s0 = fmaf(dy, dy, s0);
            dot0 = fmaf(dx, jx[k].x, dot0); dot0 = fmaf(dy, jx[k].y, dot0);
            float ex = a1[k].x - b[k].x, ey = a1[k].y - b[k].y;
            s1 = fmaf(ex, ex, s1); s1 = fmaf(ey, ey, s1);
            dot1 = fmaf(ex, jx[k].x, dot1); dot1 = fmaf(ey, jx[k].y, dot1);
        }
        // reduce across the 16-lane group (4 rows progress per wave instr)
#pragma unroll
        for (int mask = 1; mask < 16; mask <<= 1) {
            s0 += __shfl_xor(s0, mask);
            dot0 += __shfl_xor(dot0, mask);
            s1 += __shfl_xor(s1, mask);
            dot1 += __shfl_xor(dot1, mask);
        }
        float xd0 = q * sqrtf(s0), xd1 = q * sqrtf(s1);
        float e0 = k0 * __expf(-xd0), e1 = k0 * __expf(-xd1);
        float w10 = e0 * dot0 * q2, w11 = e1 * dot1 * q2;  // for raw-diff F1
        float w20 = e0 * (1.f + xd0), w21 = e1 * (1.f + xd1);
        es0 = fmaf(w20, dot0, es0);  // Es uses w2 * (q*dot_raw)/q = w2*dot_raw
        es1 = fmaf(w21, dot1, es1);
#pragma unroll
        for (int k = 0; k < 7; k++) {
            float dx = a0[k].x - b[k].x, dy = a0[k].y - b[k].y;
            f1a0[k].x = fmaf(w10, dx, f1a0[k].x);
            f1a0[k].y = fmaf(w10, dy, f1a0[k].y);
            f2a0[k].x = fmaf(w20, jx[k].x, f2a0[k].x);
            f2a0[k].y = fmaf(w20, jx[k].y, f2a0[k].y);
            float ex = a1[k].x - b[k].x, ey = a1[k].y - b[k].y;
            f1a1[k].x = fmaf(w11, ex, f1a1[k].x);
            f1a1[k].y = fmaf(w11, ey, f1a1[k].y);
            f2a1[k].x = fmaf(w21, jx[k].x, f2a1[k].x);
            f2a1[k].y = fmaf(w21, jx[k].y, f2a1[k].y);
        }
    }

    // cross-group reduce: lanes l, l^16, l^32, l^48 share the same d-slots
#pragma unroll
    for (int mask = 16; mask < 64; mask <<= 1) {
        es0 += __shfl_xor(es0, mask);
        es1 += __shfl_xor(es1, mask);
#pragma unroll
        for (int k = 0; k < 7; k++) {
            f1a0[k].x += __shfl_xor(f1a0[k].x, mask);
            f1a0[k].y += __shfl_xor(f1a0[k].y, mask);
            f1a1[k].x += __shfl_xor(f1a1[k].x, mask);
            f1a1[k].y += __shfl_xor(f1a1[k].y, mask);
            f2a0[k].x += __shfl_xor(f2a0[k].x, mask);
            f2a0[k].y += __shfl_xor(f2a0[k].y, mask);
            f2a1[k].x += __shfl_xor(f2a1[k].x, mask);
            f2a1[k].y += __shfl_xor(f2a1[k].y, mask);
        }
    }
    if (lane < 16) {
        const size_t base0 = ((size_t)m0 * NCHUNK + chunk) * DESC;
        const size_t base1 = ((size_t)m1 * NCHUNK + chunk) * DESC;
#pragma unroll
        for (int k = 0; k < 7; k++) {
            int pidx = k * 16 + gl;
            if (pidx < NPAIR2) {
                int d = 2 * pidx;
                *(float2*)&pf1[base0 + d] = f1a0[k];
                *(float2*)&pf2[base0 + d] = f2a0[k];
                *(float2*)&pf1[base1 + d] = f1a1[k];
                *(float2*)&pf2[base1 + d] = f2a1[k];
            }
        }
        if (lane == 0) {
            pes[m0 * NCHUNK + chunk] = es0;
            pes[m1 * NCHUNK + chunk] = es1;
        }
    }
}

// ---------------- K3: reduce partials, final force contraction ----------------
__global__ __launch_bounds__(256) void k_final(const float* __restrict__ Rs,
                                               const float* __restrict__ pf1,
                                               const float* __restrict__ pf2,
                                               const float* __restrict__ pes,
                                               float* __restrict__ out) {
    const int m = blockIdx.x;
    const int tid = threadIdx.x;
    __shared__ float fsx[DESC];
    __shared__ float R[N_ATOMS * 3];
    if (tid < N_ATOMS * 3) R[tid] = Rs[m * N_ATOMS * 3 + tid];
    if (tid < DESC) {
        size_t base = (size_t)m * NCHUNK * DESC + tid;
        float s1 = 0.f, s2 = 0.f;
        for (int c = 0; c < NCHUNK; c++) {
            s1 += pf1[base + (size_t)c * DESC];
            s2 += pf2[base + (size_t)c * DESC];
        }
        fsx[tid] = s1 - s2;  // STD = 1
    }
    if (tid >= 192) {  // one wave sums Es partials
        int l = tid - 192;
        float es = 0.f;
        for (int c = l; c < NCHUNK; c += 64) es += pes[m * NCHUNK + c];
#pragma unroll
        for (int mask = 1; mask < 64; mask <<= 1) es += __shfl_xor(es, mask);
        if (l == 0) out[m] = es;  // C=0, STD=1
    }
    __syncthreads();
    if (tid < N_ATOMS * 3) {
        const int b = tid / 3, kk = tid % 3;
        float acc = 0.f;
        for (int a = 0; a < N_ATOMS; a++) {
            if (a == b) continue;
            float dx = R[a * 3 + 0] - R[b * 3 + 0];
            float dy = R[a * 3 + 1] - R[b * 3 + 1];
            float dz = R[a * 3 + 2] - R[b * 3 + 2];
            float d2 = dx * dx + dy * dy + dz * dz;
            float dist = sqrtf(d2);
            float inv3 = 1.0f / (d2 * dist);
            int hi = (a > b) ? a : b, lo = (a > b) ? b : a;
            int p = hi * (hi - 1) / 2 + lo;
            float diffk = (kk == 0) ? dx : ((kk == 1) ? dy : dz);
            acc = fmaf(fsx[p] * inv3, diffk, acc);
        }
        out[BATCH + m * N_ATOMS * 3 + tid] = acc;
    }
}

extern "C" void kernel_launch(void* const* d_in, const int* in_sizes, int n_in,
                              void* d_out, int out_size, void* d_ws, size_t ws_size,
                              hipStream_t stream) {
    (void)in_sizes; (void)n_in; (void)out_size; (void)ws_size;
    const float* Rs = (const float*)d_in[0];
    const float* xs_train = (const float*)d_in[1];
    const float* Jx = (const float*)d_in[2];
    float* out = (float*)d_out;

    float* ws = (float*)d_ws;
    float* xs = ws;                                  // 64*210
    float* pf1 = xs + BATCH * DESC;                  // 64*125*210
    float* pf2 = pf1 + (size_t)BATCH * NCHUNK * DESC;
    float* pes = pf2 + (size_t)BATCH * NCHUNK * DESC;  // 64*125

    k_desc<<<dim3(BATCH), dim3(256), 0, stream>>>(Rs, xs);
    k_main<<<dim3(NCHUNK * NPAIRBLK), dim3(64), 0, stream>>>(xs_train, Jx, xs,
                                                             pf1, pf2, pes);
    k_final<<<dim3(BATCH), dim3(256), 0, stream>>>(Rs, pf1, pf2, pes, out);
}